// Round 1
// baseline (59554.413 us; speedup 1.0000x reference)
//
#include <hip/hip_runtime.h>
#include <math.h>

// LSTMCharTagger: char biLSTM (both dirs scan forward, batch 8192, T=16)
// -> gather last char -> word biLSTM (batch 1, S=8192 sequential) -> logits -> log_softmax.
// Round 1: correctness-first, all f32. Word scan = 8 WGs/dir, Whh f32 in LDS,
// per-step cross-WG sync via agent-scope atomics (flags zeroed each launch).

#define SW 8192
#define TC 16
#define ECD 64
#define HCD 128
#define DWD 300
#define HWD 256
#define DIND 556
#define NTAGS 50

__device__ __forceinline__ float sigf(float x) { return 1.f / (1.f + expf(-x)); }

#define BM 64
#define BN 64
#define BK 16

// C[M,N] = A1@W1^T (+ A2@W2^T) + bias.  A1 rows optionally gathered via idx1.
__global__ __launch_bounds__(256) void gemm2(
    const float* __restrict__ A1, int lda1, const int* __restrict__ idx1,
    const float* __restrict__ W1, int ldw1, int K1,
    const float* __restrict__ A2, int lda2,
    const float* __restrict__ W2, int ldw2, int K2,
    const float* __restrict__ bias, float* __restrict__ C, int N, int ldc)
{
    __shared__ float As[BK][BM + 4];
    __shared__ float Ws[BK][BN + 4];
    const int tid = threadIdx.x;
    const int m0 = blockIdx.y * BM;
    const int n0 = blockIdx.x * BN;
    const int tx = tid & 15, ty = tid >> 4;
    const int lr = tid >> 2;
    const int lk4 = (tid & 3) << 2;

    float acc[4][4] = {};

    for (int part = 0; part < 2; ++part) {
        const int K = part ? K2 : K1;
        if (K == 0) continue;
        const float* A = part ? A2 : A1;
        const float* W = part ? W2 : W1;
        const int* idx = part ? (const int*)nullptr : idx1;
        const int lda = part ? lda2 : lda1;
        const int ldw = part ? ldw2 : ldw1;
        const int arow = idx ? idx[m0 + lr] : (m0 + lr);
        const float* Ab = A + (size_t)arow * lda;
        const int wrow = n0 + lr;
        const bool wv = wrow < N;
        const float* Wb = W + (size_t)(wv ? wrow : 0) * ldw;
        for (int k0 = 0; k0 < K; k0 += BK) {
            const int k = k0 + lk4;
            float4 av, bv;
            if (k + 3 < K) {
                av = *(const float4*)(Ab + k);
            } else {
                av.x = (k + 0 < K) ? Ab[k + 0] : 0.f;
                av.y = (k + 1 < K) ? Ab[k + 1] : 0.f;
                av.z = (k + 2 < K) ? Ab[k + 2] : 0.f;
                av.w = (k + 3 < K) ? Ab[k + 3] : 0.f;
            }
            if (wv && (k + 3 < K)) {
                bv = *(const float4*)(Wb + k);
            } else if (wv) {
                bv.x = (k + 0 < K) ? Wb[k + 0] : 0.f;
                bv.y = (k + 1 < K) ? Wb[k + 1] : 0.f;
                bv.z = (k + 2 < K) ? Wb[k + 2] : 0.f;
                bv.w = (k + 3 < K) ? Wb[k + 3] : 0.f;
            } else {
                bv.x = bv.y = bv.z = bv.w = 0.f;
            }
            As[lk4 + 0][lr] = av.x;
            As[lk4 + 1][lr] = av.y;
            As[lk4 + 2][lr] = av.z;
            As[lk4 + 3][lr] = av.w;
            Ws[lk4 + 0][lr] = bv.x;
            Ws[lk4 + 1][lr] = bv.y;
            Ws[lk4 + 2][lr] = bv.z;
            Ws[lk4 + 3][lr] = bv.w;
            __syncthreads();
#pragma unroll
            for (int kk = 0; kk < BK; ++kk) {
                const float4 a = *(const float4*)&As[kk][ty << 2];
                const float4 b = *(const float4*)&Ws[kk][tx << 2];
                acc[0][0] += a.x * b.x; acc[0][1] += a.x * b.y; acc[0][2] += a.x * b.z; acc[0][3] += a.x * b.w;
                acc[1][0] += a.y * b.x; acc[1][1] += a.y * b.y; acc[1][2] += a.y * b.z; acc[1][3] += a.y * b.w;
                acc[2][0] += a.z * b.x; acc[2][1] += a.z * b.y; acc[2][2] += a.z * b.z; acc[2][3] += a.z * b.w;
                acc[3][0] += a.w * b.x; acc[3][1] += a.w * b.y; acc[3][2] += a.w * b.z; acc[3][3] += a.w * b.w;
            }
            __syncthreads();
        }
    }
#pragma unroll
    for (int i = 0; i < 4; ++i) {
        const int m = m0 + (ty << 2) + i;
#pragma unroll
        for (int j = 0; j < 4; ++j) {
            const int n = n0 + (tx << 2) + j;
            if (n < N) C[(size_t)m * ldc + n] = acc[i][j] + (bias ? bias[n] : 0.f);
        }
    }
}

__global__ __launch_bounds__(256) void build_cidx(const int* __restrict__ char_ix,
                                                  int* __restrict__ cidx)
{
    const int id = blockIdx.x * 256 + threadIdx.x;   // t*SW + s
    const int t = id >> 13, s = id & (SW - 1);
    cidx[id] = char_ix[s * TC + t];
}

// gates [SW][512] (i,f,g,o x128); updates c,h [SW][128];
// o_out: write h at row stride 256 (or null); crepr: write h where char_len-1==t (or null).
__global__ __launch_bounds__(256) void lstm_cell_char(
    const float* __restrict__ gates, float* __restrict__ c, float* __restrict__ h,
    float* __restrict__ o_out, float* __restrict__ crepr,
    const int* __restrict__ char_len, int t)
{
    const int id = blockIdx.x * 256 + threadIdx.x;
    const int s = id >> 7, j = id & (HCD - 1);
    const float* g = gates + (size_t)s * 512;
    const float gi = g[j], gf = g[HCD + j], gg = g[2 * HCD + j], go = g[3 * HCD + j];
    const float cn = sigf(gf) * c[id] + sigf(gi) * tanhf(gg);
    const float hn = sigf(go) * tanhf(cn);
    c[id] = cn;
    h[id] = hn;
    if (o_out) o_out[(size_t)s * 256 + j] = hn;
    if (crepr && (char_len[s] - 1 == t)) crepr[(size_t)s * 256 + j] = hn;
}

// Word-LSTM scan. Grid = 16 blocks: d = blk>>3 (0 fwd, 1 bwd), bb = blk&7.
// Block owns h-slice [32*bb,32*bb+32) -> 128 gate rows. Whh slice f32 in LDS.
// Per-step cross-block h exchange through `out` with agent-scope atomics + flags.
__global__ __launch_bounds__(256, 1) void word_scan(
    const float* __restrict__ G,     // [2][SW][1024] precomputed x@Wih^T + b
    const float* __restrict__ Whh,   // [2][1024][256]
    float* __restrict__ out,         // [SW][512]; fwd cols 0..255, bwd 256..511
    int* __restrict__ flags)         // [2][SW][8], zeroed before launch
{
    const int d = blockIdx.x >> 3;
    const int bb = blockIdx.x & 7;
    __shared__ float Wl[128][260];
    __shared__ float hl[256];
    __shared__ float gl[128];
    __shared__ float cl[32];
    const int tid = threadIdx.x;

    for (int i = tid; i < 128 * 256; i += 256) {
        const int r = i >> 8, k = i & 255;
        const int row = ((r >> 5) << 8) + (bb << 5) + (r & 31);
        Wl[r][k] = Whh[((size_t)d << 18) + (size_t)row * 256 + k];
    }
    if (tid < 32) cl[tid] = 0.f;
    __syncthreads();

    const int r = tid >> 1, hf = tid & 1;
    const int grow = ((r >> 5) << 8) + (bb << 5) + (r & 31);
    const int doff = d << 8;
    const float* Gd = G + ((size_t)d * SW * 1024);
    const int fb = d * SW * 8;
    const int tstart = d ? (SW - 1) : 0;
    const int tstep = d ? -1 : 1;

    for (int it = 0; it < SW; ++it) {
        const int t = tstart + tstep * it;
        float gin = 0.f;
        if (hf == 0) gin = Gd[(size_t)t * 1024 + grow];   // prefetch, no dep on flags
        if (it == 0) {
            hl[tid] = 0.f;
        } else {
            const int tp = t - tstep;
            if (tid < 8) {
                while (__hip_atomic_load(&flags[fb + tp * 8 + tid],
                                         __ATOMIC_ACQUIRE, __HIP_MEMORY_SCOPE_AGENT) == 0)
                    __builtin_amdgcn_s_sleep(1);
            }
            __syncthreads();
            hl[tid] = __hip_atomic_load(&out[(size_t)tp * 512 + doff + tid],
                                        __ATOMIC_RELAXED, __HIP_MEMORY_SCOPE_AGENT);
        }
        __syncthreads();

        float a0 = 0.f, a1 = 0.f, a2 = 0.f, a3 = 0.f;
        const int kb = hf << 7;
        const float* hp = &hl[kb];
        const float* wp = &Wl[r][kb];
#pragma unroll 8
        for (int k4 = 0; k4 < 32; ++k4) {
            const float4 hv = *(const float4*)(hp + (k4 << 2));
            const float4 wv = *(const float4*)(wp + (k4 << 2));
            a0 += wv.x * hv.x;
            a1 += wv.y * hv.y;
            a2 += wv.z * hv.z;
            a3 += wv.w * hv.w;
        }
        float accv = (a0 + a1) + (a2 + a3);
        accv += __shfl_xor(accv, 1);
        if (hf == 0) gl[r] = accv + gin;
        __syncthreads();
        if (tid < 32) {
            const float gi = gl[tid], gfv = gl[32 + tid], gg = gl[64 + tid], go = gl[96 + tid];
            const float cn = sigf(gfv) * cl[tid] + sigf(gi) * tanhf(gg);
            const float hn = sigf(go) * tanhf(cn);
            cl[tid] = cn;
            __hip_atomic_store(&out[(size_t)t * 512 + doff + (bb << 5) + tid], hn,
                               __ATOMIC_RELAXED, __HIP_MEMORY_SCOPE_AGENT);
        }
        __threadfence();
        __syncthreads();
        if (tid == 0)
            __hip_atomic_store(&flags[fb + t * 8 + bb], 1,
                               __ATOMIC_RELEASE, __HIP_MEMORY_SCOPE_AGENT);
    }
}

__global__ __launch_bounds__(256) void logsoftmax50(const float* __restrict__ X,
                                                    float* __restrict__ Y)
{
    const int gw = (blockIdx.x * 256 + threadIdx.x) >> 6;
    const int lane = threadIdx.x & 63;
    if (gw >= SW) return;
    const float v = (lane < NTAGS) ? X[(size_t)gw * NTAGS + lane] : -3.4e38f;
    float m = v;
#pragma unroll
    for (int o = 32; o; o >>= 1) m = fmaxf(m, __shfl_xor(m, o));
    const float e = (lane < NTAGS) ? expf(v - m) : 0.f;
    float sum = e;
#pragma unroll
    for (int o = 32; o; o >>= 1) sum += __shfl_xor(sum, o);
    if (lane < NTAGS) Y[(size_t)gw * NTAGS + lane] = v - m - logf(sum);
}

extern "C" void kernel_launch(void* const* d_in, const int* in_sizes, int n_in,
                              void* d_out, int out_size, void* d_ws, size_t ws_size,
                              hipStream_t stream)
{
    const int* word_ix  = (const int*)d_in[0];
    const int* char_ix  = (const int*)d_in[1];
    const int* char_len = (const int*)d_in[2];
    const float* word_emb = (const float*)d_in[3];
    const float* char_emb = (const float*)d_in[4];
    const float* cW_ih0 = (const float*)d_in[5];
    const float* cW_hh0 = (const float*)d_in[6];
    const float* cb0    = (const float*)d_in[7];
    const float* cW_ih1 = (const float*)d_in[8];
    const float* cW_hh1 = (const float*)d_in[9];
    const float* cb1    = (const float*)d_in[10];
    const float* wW_ih0 = (const float*)d_in[11];
    const float* wW_hh0 = (const float*)d_in[12];
    const float* wb0    = (const float*)d_in[13];
    const float* wW_ih1 = (const float*)d_in[14];
    const float* wW_hh1 = (const float*)d_in[15];
    const float* wb1    = (const float*)d_in[16];
    const float* out_W  = (const float*)d_in[17];
    const float* out_b  = (const float*)d_in[18];
    float* Y = (float*)d_out;
    (void)in_sizes; (void)n_in; (void)out_size; (void)ws_size;

    char* p = (char*)d_ws;
    auto alloc = [&](size_t bytes) { char* q = p; p += (bytes + 255) & ~(size_t)255; return q; };
    int*   flags = (int*)  alloc(2ull * 2 * SW * 8 * 4);       // [layer][dir][SW][8]
    float* ch_h  = (float*)alloc(4ull * SW * HCD * 4);         // [layer*2+dir][SW][HCD]
    float* ch_c  = (float*)alloc(4ull * SW * HCD * 4);
    const size_t zbytes = (size_t)(p - (char*)d_ws);           // zero: flags + ch_h + ch_c
    float* gates = (float*)alloc(2ull * SW * 512 * 4);         // per-dir char gates / logits tmp
    float* o0s   = (float*)alloc((size_t)SW * 256 * 4);        // layer-0 output, current t only
    float* crepr = (float*)alloc((size_t)SW * 256 * 4);
    float* wG    = (float*)alloc(2ull * SW * 1024 * 4);        // word gate inputs (reused L0->L1)
    float* wo0   = (float*)alloc((size_t)SW * 512 * 4);
    float* wo1   = (float*)alloc((size_t)SW * 512 * 4);
    int*   cidx  = (int*)  alloc((size_t)TC * SW * 4);

    hipMemsetAsync(d_ws, 0, zbytes, stream);
    build_cidx<<<TC * SW / 256, 256, 0, stream>>>(char_ix, cidx);

    // ---- char biLSTM: L0 and L1 interleaved per timestep (o0s is one-step ring) ----
    for (int t = 0; t < TC; ++t) {
        for (int d = 0; d < 2; ++d)
            gemm2<<<dim3(512 / BN, SW / BM), 256, 0, stream>>>(
                char_emb, ECD, cidx + t * SW, cW_ih0 + (size_t)d * 512 * ECD, ECD, ECD,
                ch_h + (size_t)d * SW * HCD, HCD, cW_hh0 + (size_t)d * 512 * HCD, HCD, HCD,
                cb0 + d * 512, gates + (size_t)d * SW * 512, 512, 512);
        for (int d = 0; d < 2; ++d)
            lstm_cell_char<<<SW * HCD / 256, 256, 0, stream>>>(
                gates + (size_t)d * SW * 512, ch_c + (size_t)d * SW * HCD,
                ch_h + (size_t)d * SW * HCD, o0s + d * HCD, nullptr, nullptr, t);
        for (int d = 0; d < 2; ++d)
            gemm2<<<dim3(512 / BN, SW / BM), 256, 0, stream>>>(
                o0s, 256, nullptr, cW_ih1 + (size_t)d * 512 * 256, 256, 256,
                ch_h + (size_t)(2 + d) * SW * HCD, HCD, cW_hh1 + (size_t)d * 512 * HCD, HCD, HCD,
                cb1 + d * 512, gates + (size_t)d * SW * 512, 512, 512);
        for (int d = 0; d < 2; ++d)
            lstm_cell_char<<<SW * HCD / 256, 256, 0, stream>>>(
                gates + (size_t)d * SW * 512, ch_c + (size_t)(2 + d) * SW * HCD,
                ch_h + (size_t)(2 + d) * SW * HCD, nullptr, crepr + d * HCD, char_len, t);
    }

    // ---- word biLSTM layer 0 ----
    for (int d = 0; d < 2; ++d)
        gemm2<<<dim3(1024 / BN, SW / BM), 256, 0, stream>>>(
            word_emb, DWD, word_ix, wW_ih0 + (size_t)d * 1024 * DIND, DIND, DWD,
            crepr, 256, wW_ih0 + (size_t)d * 1024 * DIND + DWD, DIND, 256,
            wb0 + d * 1024, wG + (size_t)d * SW * 1024, 1024, 1024);
    word_scan<<<16, 256, 0, stream>>>(wG, wW_hh0, wo0, flags);

    // ---- word biLSTM layer 1 ----
    for (int d = 0; d < 2; ++d)
        gemm2<<<dim3(1024 / BN, SW / BM), 256, 0, stream>>>(
            wo0, 512, nullptr, wW_ih1 + (size_t)d * 1024 * 512, 512, 512,
            nullptr, 0, nullptr, 0, 0,
            wb1 + d * 1024, wG + (size_t)d * SW * 1024, 1024, 1024);
    word_scan<<<16, 256, 0, stream>>>(wG, wW_hh1, wo1, flags + 2 * SW * 8);

    // ---- logits + log_softmax ----
    gemm2<<<dim3(1, SW / BM), 256, 0, stream>>>(
        wo1, 512, nullptr, out_W, 512, 512,
        nullptr, 0, nullptr, 0, 0,
        out_b, gates, NTAGS, NTAGS);
    logsoftmax50<<<SW * 64 / 256, 256, 0, stream>>>(gates, Y);
}

// Round 2
// 43193.341 us; speedup vs baseline: 1.3788x; 1.3788x over previous
//
#include <hip/hip_runtime.h>
#include <math.h>

// LSTMCharTagger: char biLSTM (both dirs scan forward, batch 8192, T=16)
// -> gather last char -> word biLSTM (batch 1, S=8192 sequential) -> logits -> log_softmax.
// R2: word_scan rewritten — Whh in VGPRs (128 f32/thread), h broadcast via LDS,
// cross-block sync = relaxed sc1 atomics + one RELEASE fetch_add counter/step.

#define SW 8192
#define TC 16
#define ECD 64
#define HCD 128
#define DWD 300
#define HWD 256
#define DIND 556
#define NTAGS 50

__device__ __forceinline__ float sigf(float x) { return 1.f / (1.f + expf(-x)); }

#define BM 64
#define BN 64
#define BK 16

// C[M,N] = A1@W1^T (+ A2@W2^T) + bias.  A1 rows optionally gathered via idx1.
__global__ __launch_bounds__(256) void gemm2(
    const float* __restrict__ A1, int lda1, const int* __restrict__ idx1,
    const float* __restrict__ W1, int ldw1, int K1,
    const float* __restrict__ A2, int lda2,
    const float* __restrict__ W2, int ldw2, int K2,
    const float* __restrict__ bias, float* __restrict__ C, int N, int ldc)
{
    __shared__ float As[BK][BM + 4];
    __shared__ float Ws[BK][BN + 4];
    const int tid = threadIdx.x;
    const int m0 = blockIdx.y * BM;
    const int n0 = blockIdx.x * BN;
    const int tx = tid & 15, ty = tid >> 4;
    const int lr = tid >> 2;
    const int lk4 = (tid & 3) << 2;

    float acc[4][4] = {};

    for (int part = 0; part < 2; ++part) {
        const int K = part ? K2 : K1;
        if (K == 0) continue;
        const float* A = part ? A2 : A1;
        const float* W = part ? W2 : W1;
        const int* idx = part ? (const int*)nullptr : idx1;
        const int lda = part ? lda2 : lda1;
        const int ldw = part ? ldw2 : ldw1;
        const int arow = idx ? idx[m0 + lr] : (m0 + lr);
        const float* Ab = A + (size_t)arow * lda;
        const int wrow = n0 + lr;
        const bool wv = wrow < N;
        const float* Wb = W + (size_t)(wv ? wrow : 0) * ldw;
        for (int k0 = 0; k0 < K; k0 += BK) {
            const int k = k0 + lk4;
            float4 av, bv;
            if (k + 3 < K) {
                av = *(const float4*)(Ab + k);
            } else {
                av.x = (k + 0 < K) ? Ab[k + 0] : 0.f;
                av.y = (k + 1 < K) ? Ab[k + 1] : 0.f;
                av.z = (k + 2 < K) ? Ab[k + 2] : 0.f;
                av.w = (k + 3 < K) ? Ab[k + 3] : 0.f;
            }
            if (wv && (k + 3 < K)) {
                bv = *(const float4*)(Wb + k);
            } else if (wv) {
                bv.x = (k + 0 < K) ? Wb[k + 0] : 0.f;
                bv.y = (k + 1 < K) ? Wb[k + 1] : 0.f;
                bv.z = (k + 2 < K) ? Wb[k + 2] : 0.f;
                bv.w = (k + 3 < K) ? Wb[k + 3] : 0.f;
            } else {
                bv.x = bv.y = bv.z = bv.w = 0.f;
            }
            As[lk4 + 0][lr] = av.x;
            As[lk4 + 1][lr] = av.y;
            As[lk4 + 2][lr] = av.z;
            As[lk4 + 3][lr] = av.w;
            Ws[lk4 + 0][lr] = bv.x;
            Ws[lk4 + 1][lr] = bv.y;
            Ws[lk4 + 2][lr] = bv.z;
            Ws[lk4 + 3][lr] = bv.w;
            __syncthreads();
#pragma unroll
            for (int kk = 0; kk < BK; ++kk) {
                const float4 a = *(const float4*)&As[kk][ty << 2];
                const float4 b = *(const float4*)&Ws[kk][tx << 2];
                acc[0][0] += a.x * b.x; acc[0][1] += a.x * b.y; acc[0][2] += a.x * b.z; acc[0][3] += a.x * b.w;
                acc[1][0] += a.y * b.x; acc[1][1] += a.y * b.y; acc[1][2] += a.y * b.z; acc[1][3] += a.y * b.w;
                acc[2][0] += a.z * b.x; acc[2][1] += a.z * b.y; acc[2][2] += a.z * b.z; acc[2][3] += a.z * b.w;
                acc[3][0] += a.w * b.x; acc[3][1] += a.w * b.y; acc[3][2] += a.w * b.z; acc[3][3] += a.w * b.w;
            }
            __syncthreads();
        }
    }
#pragma unroll
    for (int i = 0; i < 4; ++i) {
        const int m = m0 + (ty << 2) + i;
#pragma unroll
        for (int j = 0; j < 4; ++j) {
            const int n = n0 + (tx << 2) + j;
            if (n < N) C[(size_t)m * ldc + n] = acc[i][j] + (bias ? bias[n] : 0.f);
        }
    }
}

__global__ __launch_bounds__(256) void build_cidx(const int* __restrict__ char_ix,
                                                  int* __restrict__ cidx)
{
    const int id = blockIdx.x * 256 + threadIdx.x;   // t*SW + s
    const int t = id >> 13, s = id & (SW - 1);
    cidx[id] = char_ix[s * TC + t];
}

// gates [SW][512] (i,f,g,o x128); updates c,h [SW][128];
// o_out: write h at row stride 256 (or null); crepr: write h where char_len-1==t (or null).
__global__ __launch_bounds__(256) void lstm_cell_char(
    const float* __restrict__ gates, float* __restrict__ c, float* __restrict__ h,
    float* __restrict__ o_out, float* __restrict__ crepr,
    const int* __restrict__ char_len, int t)
{
    const int id = blockIdx.x * 256 + threadIdx.x;
    const int s = id >> 7, j = id & (HCD - 1);
    const float* g = gates + (size_t)s * 512;
    const float gi = g[j], gf = g[HCD + j], gg = g[2 * HCD + j], go = g[3 * HCD + j];
    const float cn = sigf(gf) * c[id] + sigf(gi) * tanhf(gg);
    const float hn = sigf(go) * tanhf(cn);
    c[id] = cn;
    h[id] = hn;
    if (o_out) o_out[(size_t)s * 256 + j] = hn;
    if (crepr && (char_len[s] - 1 == t)) crepr[(size_t)s * 256 + j] = hn;
}

// Word-LSTM scan v2. Grid = 16 blocks: d = blk>>3 (0 fwd, 1 bwd), bb = blk&7.
// Block owns h-slice [32*bb, 32*bb+32) -> 128 gate rows (4 gates x 32).
// Thread t: row r=t>>1 (local), half hf=t&1; W[grow][hf*128..+128) kept in 32 float4 VGPRs.
// h exchange: sc1 relaxed atomics to `out`; per-step counter cnt[t], RELEASE fetch_add by
// producer wave, RELAXED spin by consumers (poll also orders producer wave vs next step).
__global__ __launch_bounds__(256, 1) void word_scan(
    const float* __restrict__ G,     // [2][SW][1024] precomputed x@Wih^T + b
    const float* __restrict__ Whh,   // [2][1024][256]
    float* __restrict__ out,         // [SW][512]; fwd cols 0..255, bwd 256..511
    int* __restrict__ cnt)           // [2][SW], zeroed before launch
{
    const int d = blockIdx.x >> 3;
    const int bb = blockIdx.x & 7;
    __shared__ float hl[264];        // halves at [0..128) and [132..260): disjoint banks
    __shared__ float gl[128];        // activated gates: [0:32)=sig(i) [32)=sig(f) [64)=tanh(g) [96)=sig(o)
    const int tid = threadIdx.x;
    const int r = tid >> 1, hf = tid & 1;
    const int wq = tid >> 6;                                 // wave id == gate index (uniform)
    const int grow = ((r >> 5) << 8) + (bb << 5) + (r & 31); // global gate row

    // --- load W row-half into registers (once) ---
    const float* wrow = Whh + ((size_t)d << 18) + (size_t)grow * 256 + (hf << 7);
    float4 w[32];
#pragma unroll
    for (int k = 0; k < 32; ++k) w[k] = *(const float4*)(wrow + (k << 2));

    const float* Gd = G + ((size_t)d * SW * 1024);
    float* outd = out + (d << 8);
    int* cntd = cnt + d * SW;
    const int hlix = tid + ((tid >> 7) << 2);
    const float* hp = &hl[hf ? 132 : 0];
    const int tstart = d ? (SW - 1) : 0;
    const int tstep = d ? -1 : 1;
    float creg = 0.f;

    for (int it = 0; it < SW; ++it) {
        const int t = tstart + tstep * it;
        float gval = 0.f;
        if (hf == 0) gval = Gd[(size_t)t * 1024 + grow];   // independent prefetch
        if (it) {
            const int tp = t - tstep;
            while (__hip_atomic_load(&cntd[tp], __ATOMIC_RELAXED, __HIP_MEMORY_SCOPE_AGENT) < 8)
                __builtin_amdgcn_s_sleep(1);
            hl[hlix] = __hip_atomic_load(&outd[(size_t)tp * 512 + tid],
                                         __ATOMIC_RELAXED, __HIP_MEMORY_SCOPE_AGENT);
        } else {
            hl[hlix] = 0.f;
        }
        __syncthreads();

        float a0 = 0.f, a1 = 0.f, a2 = 0.f, a3 = 0.f;
#pragma unroll
        for (int k = 0; k < 32; ++k) {
            const float4 hv = *(const float4*)(hp + (k << 2));
            a0 = fmaf(w[k].x, hv.x, a0);
            a1 = fmaf(w[k].y, hv.y, a1);
            a2 = fmaf(w[k].z, hv.z, a2);
            a3 = fmaf(w[k].w, hv.w, a3);
        }
        float s = (a0 + a1) + (a2 + a3);
        s += __shfl_xor(s, 1);
        if (hf == 0) {
            s += gval;
            gl[r] = (wq == 2) ? tanhf(s) : sigf(s);   // wave-uniform branch
        }
        __syncthreads();

        if (tid < 32) {
            const float cn = gl[32 + tid] * creg + gl[tid] * gl[64 + tid];
            const float hn = gl[96 + tid] * tanhf(cn);
            creg = cn;
            __hip_atomic_store(&outd[(size_t)t * 512 + (bb << 5) + tid], hn,
                               __ATOMIC_RELAXED, __HIP_MEMORY_SCOPE_AGENT);
        }
        if (tid == 0)
            __hip_atomic_fetch_add(&cntd[t], 1, __ATOMIC_RELEASE, __HIP_MEMORY_SCOPE_AGENT);
        // next-iteration poll (cnt needs own +1) orders every wave vs LDS overwrite
    }
}

__global__ __launch_bounds__(256) void logsoftmax50(const float* __restrict__ X,
                                                    float* __restrict__ Y)
{
    const int gw = (blockIdx.x * 256 + threadIdx.x) >> 6;
    const int lane = threadIdx.x & 63;
    if (gw >= SW) return;
    const float v = (lane < NTAGS) ? X[(size_t)gw * NTAGS + lane] : -3.4e38f;
    float m = v;
#pragma unroll
    for (int o = 32; o; o >>= 1) m = fmaxf(m, __shfl_xor(m, o));
    const float e = (lane < NTAGS) ? expf(v - m) : 0.f;
    float sum = e;
#pragma unroll
    for (int o = 32; o; o >>= 1) sum += __shfl_xor(sum, o);
    if (lane < NTAGS) Y[(size_t)gw * NTAGS + lane] = v - m - logf(sum);
}

extern "C" void kernel_launch(void* const* d_in, const int* in_sizes, int n_in,
                              void* d_out, int out_size, void* d_ws, size_t ws_size,
                              hipStream_t stream)
{
    const int* word_ix  = (const int*)d_in[0];
    const int* char_ix  = (const int*)d_in[1];
    const int* char_len = (const int*)d_in[2];
    const float* word_emb = (const float*)d_in[3];
    const float* char_emb = (const float*)d_in[4];
    const float* cW_ih0 = (const float*)d_in[5];
    const float* cW_hh0 = (const float*)d_in[6];
    const float* cb0    = (const float*)d_in[7];
    const float* cW_ih1 = (const float*)d_in[8];
    const float* cW_hh1 = (const float*)d_in[9];
    const float* cb1    = (const float*)d_in[10];
    const float* wW_ih0 = (const float*)d_in[11];
    const float* wW_hh0 = (const float*)d_in[12];
    const float* wb0    = (const float*)d_in[13];
    const float* wW_ih1 = (const float*)d_in[14];
    const float* wW_hh1 = (const float*)d_in[15];
    const float* wb1    = (const float*)d_in[16];
    const float* out_W  = (const float*)d_in[17];
    const float* out_b  = (const float*)d_in[18];
    float* Y = (float*)d_out;
    (void)in_sizes; (void)n_in; (void)out_size; (void)ws_size;

    char* p = (char*)d_ws;
    auto alloc = [&](size_t bytes) { char* q = p; p += (bytes + 255) & ~(size_t)255; return q; };
    int*   cnt   = (int*)  alloc(2ull * 2 * SW * 4);           // [layer][dir][SW] step counters
    float* ch_h  = (float*)alloc(4ull * SW * HCD * 4);         // [layer*2+dir][SW][HCD]
    float* ch_c  = (float*)alloc(4ull * SW * HCD * 4);
    const size_t zbytes = (size_t)(p - (char*)d_ws);           // zero: cnt + ch_h + ch_c
    float* gates = (float*)alloc(2ull * SW * 512 * 4);         // per-dir char gates / logits tmp
    float* o0s   = (float*)alloc((size_t)SW * 256 * 4);        // layer-0 output, current t only
    float* crepr = (float*)alloc((size_t)SW * 256 * 4);
    float* wG    = (float*)alloc(2ull * SW * 1024 * 4);        // word gate inputs (reused L0->L1)
    float* wo0   = (float*)alloc((size_t)SW * 512 * 4);
    float* wo1   = (float*)alloc((size_t)SW * 512 * 4);
    int*   cidx  = (int*)  alloc((size_t)TC * SW * 4);

    hipMemsetAsync(d_ws, 0, zbytes, stream);
    build_cidx<<<TC * SW / 256, 256, 0, stream>>>(char_ix, cidx);

    // ---- char biLSTM: L0 and L1 interleaved per timestep (o0s is one-step ring) ----
    for (int t = 0; t < TC; ++t) {
        for (int d = 0; d < 2; ++d)
            gemm2<<<dim3(512 / BN, SW / BM), 256, 0, stream>>>(
                char_emb, ECD, cidx + t * SW, cW_ih0 + (size_t)d * 512 * ECD, ECD, ECD,
                ch_h + (size_t)d * SW * HCD, HCD, cW_hh0 + (size_t)d * 512 * HCD, HCD, HCD,
                cb0 + d * 512, gates + (size_t)d * SW * 512, 512, 512);
        for (int d = 0; d < 2; ++d)
            lstm_cell_char<<<SW * HCD / 256, 256, 0, stream>>>(
                gates + (size_t)d * SW * 512, ch_c + (size_t)d * SW * HCD,
                ch_h + (size_t)d * SW * HCD, o0s + d * HCD, nullptr, nullptr, t);
        for (int d = 0; d < 2; ++d)
            gemm2<<<dim3(512 / BN, SW / BM), 256, 0, stream>>>(
                o0s, 256, nullptr, cW_ih1 + (size_t)d * 512 * 256, 256, 256,
                ch_h + (size_t)(2 + d) * SW * HCD, HCD, cW_hh1 + (size_t)d * 512 * HCD, HCD, HCD,
                cb1 + d * 512, gates + (size_t)d * SW * 512, 512, 512);
        for (int d = 0; d < 2; ++d)
            lstm_cell_char<<<SW * HCD / 256, 256, 0, stream>>>(
                gates + (size_t)d * SW * 512, ch_c + (size_t)(2 + d) * SW * HCD,
                ch_h + (size_t)(2 + d) * SW * HCD, nullptr, crepr + d * HCD, char_len, t);
    }

    // ---- word biLSTM layer 0 ----
    for (int d = 0; d < 2; ++d)
        gemm2<<<dim3(1024 / BN, SW / BM), 256, 0, stream>>>(
            word_emb, DWD, word_ix, wW_ih0 + (size_t)d * 1024 * DIND, DIND, DWD,
            crepr, 256, wW_ih0 + (size_t)d * 1024 * DIND + DWD, DIND, 256,
            wb0 + d * 1024, wG + (size_t)d * SW * 1024, 1024, 1024);
    word_scan<<<16, 256, 0, stream>>>(wG, wW_hh0, wo0, cnt);

    // ---- word biLSTM layer 1 ----
    for (int d = 0; d < 2; ++d)
        gemm2<<<dim3(1024 / BN, SW / BM), 256, 0, stream>>>(
            wo0, 512, nullptr, wW_ih1 + (size_t)d * 1024 * 512, 512, 512,
            nullptr, 0, nullptr, 0, 0,
            wb1 + d * 1024, wG + (size_t)d * SW * 1024, 1024, 1024);
    word_scan<<<16, 256, 0, stream>>>(wG, wW_hh1, wo1, cnt + 2 * SW);

    // ---- logits + log_softmax ----
    gemm2<<<dim3(1, SW / BM), 256, 0, stream>>>(
        wo1, 512, nullptr, out_W, 512, 512,
        nullptr, 0, nullptr, 0, 0,
        out_b, gates, NTAGS, NTAGS);
    logsoftmax50<<<SW * 64 / 256, 256, 0, stream>>>(gates, Y);
}

// Round 3
// 37981.827 us; speedup vs baseline: 1.5680x; 1.1372x over previous
//
#include <hip/hip_runtime.h>
#include <math.h>

// LSTMCharTagger: char biLSTM (both dirs scan forward, batch 8192, T=16)
// -> gather last char -> word biLSTM (batch 1, S=8192 sequential) -> logits -> log_softmax.
// R3: word_scan v3 — 512 thr/block (W = 16 float4/thread, stays in VGPRs),
// per-(t,block) flag stores (no RMW), wave-0-only poll + h fetch.

#define SW 8192
#define TC 16
#define ECD 64
#define HCD 128
#define DWD 300
#define HWD 256
#define DIND 556
#define NTAGS 50

__device__ __forceinline__ float sigf(float x) { return 1.f / (1.f + expf(-x)); }

#define BM 64
#define BN 64
#define BK 16

// C[M,N] = A1@W1^T (+ A2@W2^T) + bias.  A1 rows optionally gathered via idx1.
__global__ __launch_bounds__(256) void gemm2(
    const float* __restrict__ A1, int lda1, const int* __restrict__ idx1,
    const float* __restrict__ W1, int ldw1, int K1,
    const float* __restrict__ A2, int lda2,
    const float* __restrict__ W2, int ldw2, int K2,
    const float* __restrict__ bias, float* __restrict__ C, int N, int ldc)
{
    __shared__ float As[BK][BM + 4];
    __shared__ float Ws[BK][BN + 4];
    const int tid = threadIdx.x;
    const int m0 = blockIdx.y * BM;
    const int n0 = blockIdx.x * BN;
    const int tx = tid & 15, ty = tid >> 4;
    const int lr = tid >> 2;
    const int lk4 = (tid & 3) << 2;

    float acc[4][4] = {};

    for (int part = 0; part < 2; ++part) {
        const int K = part ? K2 : K1;
        if (K == 0) continue;
        const float* A = part ? A2 : A1;
        const float* W = part ? W2 : W1;
        const int* idx = part ? (const int*)nullptr : idx1;
        const int lda = part ? lda2 : lda1;
        const int ldw = part ? ldw2 : ldw1;
        const int arow = idx ? idx[m0 + lr] : (m0 + lr);
        const float* Ab = A + (size_t)arow * lda;
        const int wrow = n0 + lr;
        const bool wv = wrow < N;
        const float* Wb = W + (size_t)(wv ? wrow : 0) * ldw;
        for (int k0 = 0; k0 < K; k0 += BK) {
            const int k = k0 + lk4;
            float4 av, bv;
            if (k + 3 < K) {
                av = *(const float4*)(Ab + k);
            } else {
                av.x = (k + 0 < K) ? Ab[k + 0] : 0.f;
                av.y = (k + 1 < K) ? Ab[k + 1] : 0.f;
                av.z = (k + 2 < K) ? Ab[k + 2] : 0.f;
                av.w = (k + 3 < K) ? Ab[k + 3] : 0.f;
            }
            if (wv && (k + 3 < K)) {
                bv = *(const float4*)(Wb + k);
            } else if (wv) {
                bv.x = (k + 0 < K) ? Wb[k + 0] : 0.f;
                bv.y = (k + 1 < K) ? Wb[k + 1] : 0.f;
                bv.z = (k + 2 < K) ? Wb[k + 2] : 0.f;
                bv.w = (k + 3 < K) ? Wb[k + 3] : 0.f;
            } else {
                bv.x = bv.y = bv.z = bv.w = 0.f;
            }
            As[lk4 + 0][lr] = av.x;
            As[lk4 + 1][lr] = av.y;
            As[lk4 + 2][lr] = av.z;
            As[lk4 + 3][lr] = av.w;
            Ws[lk4 + 0][lr] = bv.x;
            Ws[lk4 + 1][lr] = bv.y;
            Ws[lk4 + 2][lr] = bv.z;
            Ws[lk4 + 3][lr] = bv.w;
            __syncthreads();
#pragma unroll
            for (int kk = 0; kk < BK; ++kk) {
                const float4 a = *(const float4*)&As[kk][ty << 2];
                const float4 b = *(const float4*)&Ws[kk][tx << 2];
                acc[0][0] += a.x * b.x; acc[0][1] += a.x * b.y; acc[0][2] += a.x * b.z; acc[0][3] += a.x * b.w;
                acc[1][0] += a.y * b.x; acc[1][1] += a.y * b.y; acc[1][2] += a.y * b.z; acc[1][3] += a.y * b.w;
                acc[2][0] += a.z * b.x; acc[2][1] += a.z * b.y; acc[2][2] += a.z * b.z; acc[2][3] += a.z * b.w;
                acc[3][0] += a.w * b.x; acc[3][1] += a.w * b.y; acc[3][2] += a.w * b.z; acc[3][3] += a.w * b.w;
            }
            __syncthreads();
        }
    }
#pragma unroll
    for (int i = 0; i < 4; ++i) {
        const int m = m0 + (ty << 2) + i;
#pragma unroll
        for (int j = 0; j < 4; ++j) {
            const int n = n0 + (tx << 2) + j;
            if (n < N) C[(size_t)m * ldc + n] = acc[i][j] + (bias ? bias[n] : 0.f);
        }
    }
}

__global__ __launch_bounds__(256) void build_cidx(const int* __restrict__ char_ix,
                                                  int* __restrict__ cidx)
{
    const int id = blockIdx.x * 256 + threadIdx.x;   // t*SW + s
    const int t = id >> 13, s = id & (SW - 1);
    cidx[id] = char_ix[s * TC + t];
}

// gates [SW][512] (i,f,g,o x128); updates c,h [SW][128];
// o_out: write h at row stride 256 (or null); crepr: write h where char_len-1==t (or null).
__global__ __launch_bounds__(256) void lstm_cell_char(
    const float* __restrict__ gates, float* __restrict__ c, float* __restrict__ h,
    float* __restrict__ o_out, float* __restrict__ crepr,
    const int* __restrict__ char_len, int t)
{
    const int id = blockIdx.x * 256 + threadIdx.x;
    const int s = id >> 7, j = id & (HCD - 1);
    const float* g = gates + (size_t)s * 512;
    const float gi = g[j], gf = g[HCD + j], gg = g[2 * HCD + j], go = g[3 * HCD + j];
    const float cn = sigf(gf) * c[id] + sigf(gi) * tanhf(gg);
    const float hn = sigf(go) * tanhf(cn);
    c[id] = cn;
    h[id] = hn;
    if (o_out) o_out[(size_t)s * 256 + j] = hn;
    if (crepr && (char_len[s] - 1 == t)) crepr[(size_t)s * 256 + j] = hn;
}

// Word-LSTM scan v3. Grid = 16 blocks x 512 thr: d = blk>>3, bb = blk&7.
// Block owns h-slice [32*bb,32*bb+32) -> 128 gate rows. Thread: row r=tid>>2,
// k-quarter q=tid&3 -> W chunk = 16 float4 (64 VGPRs, stays resident).
// Sync: producer stores h (sc1) + one RELEASE flag store per (t,block);
// consumers: lanes 0-7 of wave 0 poll 8 flags, wave 0 fetches h into LDS.
__global__ __launch_bounds__(512, 1) void word_scan(
    const float* __restrict__ G,     // [2][SW][1024] precomputed x@Wih^T + b
    const float* __restrict__ Whh,   // [2][1024][256]
    float* __restrict__ out,         // [SW][512]; fwd cols 0..255, bwd 256..511
    int* __restrict__ flags)         // [2][SW][8], zeroed before launch
{
    const int d = blockIdx.x >> 3;
    const int bb = blockIdx.x & 7;
    __shared__ float hl[4 * 68];     // quarters at stride 68 floats: disjoint bank groups
    __shared__ float gl[128];        // activated gates: [0:32)=sig(i) [32)=sig(f) [64)=tanh(g) [96)=sig(o)
    const int tid = threadIdx.x;
    const int l = tid & 63;
    const int wave = tid >> 6;
    const int r = tid >> 2;                                  // local gate row 0..127
    const int q = tid & 3;                                   // k-quarter
    const int gate = r >> 5;                                 // wave-uniform (waves 2w,2w+1 -> gate w)
    const int grow = (gate << 8) + (bb << 5) + (r & 31);     // global gate row

    // --- W chunk into registers (once): rows grow, cols [64q, 64q+64) ---
    const float* wrow = Whh + ((size_t)d << 18) + (size_t)grow * 256 + (q << 6);
    float4 w[16];
#pragma unroll
    for (int k = 0; k < 16; ++k) w[k] = *(const float4*)(wrow + (k << 2));

    const float* Gd = G + ((size_t)d * SW * 1024);
    float* outd = out + (d << 8);
    int* flagd = flags + d * SW * 8;
    const float* hp = &hl[q * 68];
    const int tstart = d ? (SW - 1) : 0;
    const int tstep = d ? -1 : 1;
    float creg = 0.f;

    for (int it = 0; it < SW; ++it) {
        const int t = tstart + tstep * it;
        float gval = 0.f;
        if (q == 0) gval = Gd[(size_t)t * 1024 + grow];      // independent prefetch

        if (wave == 0) {
            const int dst = (l >> 4) * 68 + ((l & 15) << 2); // h[4l..4l+4) -> quarter layout
            if (it) {
                const int tp = t - tstep;
                int f = 1;
                for (;;) {
                    if (l < 8) f = __hip_atomic_load(&flagd[tp * 8 + l],
                                                     __ATOMIC_RELAXED, __HIP_MEMORY_SCOPE_AGENT);
                    if (__all(f != 0)) break;
                }
                __builtin_amdgcn_fence(__ATOMIC_ACQUIRE, "agent");
                const float* src = outd + (size_t)tp * 512 + (l << 2);
                float4 hv;
                hv.x = __hip_atomic_load(src + 0, __ATOMIC_RELAXED, __HIP_MEMORY_SCOPE_AGENT);
                hv.y = __hip_atomic_load(src + 1, __ATOMIC_RELAXED, __HIP_MEMORY_SCOPE_AGENT);
                hv.z = __hip_atomic_load(src + 2, __ATOMIC_RELAXED, __HIP_MEMORY_SCOPE_AGENT);
                hv.w = __hip_atomic_load(src + 3, __ATOMIC_RELAXED, __HIP_MEMORY_SCOPE_AGENT);
                *(float4*)&hl[dst] = hv;
            } else {
                *(float4*)&hl[dst] = float4{0.f, 0.f, 0.f, 0.f};
            }
        }
        __syncthreads();                                     // B1: hl ready

        float a0 = 0.f, a1 = 0.f, a2 = 0.f, a3 = 0.f;
#pragma unroll
        for (int k = 0; k < 16; ++k) {
            const float4 hv = *(const float4*)(hp + (k << 2));
            a0 = fmaf(w[k].x, hv.x, a0);
            a1 = fmaf(w[k].y, hv.y, a1);
            a2 = fmaf(w[k].z, hv.z, a2);
            a3 = fmaf(w[k].w, hv.w, a3);
        }
        float s = (a0 + a1) + (a2 + a3);
        s += __shfl_xor(s, 1);
        s += __shfl_xor(s, 2);
        if (q == 0) {
            s += gval;
            gl[r] = (gate == 2) ? tanhf(s) : sigf(s);        // wave-uniform branch
        }
        __syncthreads();                                     // B2: gl ready, hl reads done

        if (tid < 32) {
            const float cn = gl[32 + tid] * creg + gl[tid] * gl[64 + tid];
            const float hn = gl[96 + tid] * tanhf(cn);
            creg = cn;
            __hip_atomic_store(&outd[(size_t)t * 512 + (bb << 5) + tid], hn,
                               __ATOMIC_RELAXED, __HIP_MEMORY_SCOPE_AGENT);
        }
        if (tid == 0)
            __hip_atomic_store(&flagd[t * 8 + bb], 1,
                               __ATOMIC_RELEASE, __HIP_MEMORY_SCOPE_AGENT);
        // wave 0 only touches hl again after B2 of this iter; others read gl never
    }
}

__global__ __launch_bounds__(256) void logsoftmax50(const float* __restrict__ X,
                                                    float* __restrict__ Y)
{
    const int gw = (blockIdx.x * 256 + threadIdx.x) >> 6;
    const int lane = threadIdx.x & 63;
    if (gw >= SW) return;
    const float v = (lane < NTAGS) ? X[(size_t)gw * NTAGS + lane] : -3.4e38f;
    float m = v;
#pragma unroll
    for (int o = 32; o; o >>= 1) m = fmaxf(m, __shfl_xor(m, o));
    const float e = (lane < NTAGS) ? expf(v - m) : 0.f;
    float sum = e;
#pragma unroll
    for (int o = 32; o; o >>= 1) sum += __shfl_xor(sum, o);
    if (lane < NTAGS) Y[(size_t)gw * NTAGS + lane] = v - m - logf(sum);
}

extern "C" void kernel_launch(void* const* d_in, const int* in_sizes, int n_in,
                              void* d_out, int out_size, void* d_ws, size_t ws_size,
                              hipStream_t stream)
{
    const int* word_ix  = (const int*)d_in[0];
    const int* char_ix  = (const int*)d_in[1];
    const int* char_len = (const int*)d_in[2];
    const float* word_emb = (const float*)d_in[3];
    const float* char_emb = (const float*)d_in[4];
    const float* cW_ih0 = (const float*)d_in[5];
    const float* cW_hh0 = (const float*)d_in[6];
    const float* cb0    = (const float*)d_in[7];
    const float* cW_ih1 = (const float*)d_in[8];
    const float* cW_hh1 = (const float*)d_in[9];
    const float* cb1    = (const float*)d_in[10];
    const float* wW_ih0 = (const float*)d_in[11];
    const float* wW_hh0 = (const float*)d_in[12];
    const float* wb0    = (const float*)d_in[13];
    const float* wW_ih1 = (const float*)d_in[14];
    const float* wW_hh1 = (const float*)d_in[15];
    const float* wb1    = (const float*)d_in[16];
    const float* out_W  = (const float*)d_in[17];
    const float* out_b  = (const float*)d_in[18];
    float* Y = (float*)d_out;
    (void)in_sizes; (void)n_in; (void)out_size; (void)ws_size;

    char* p = (char*)d_ws;
    auto alloc = [&](size_t bytes) { char* q = p; p += (bytes + 255) & ~(size_t)255; return q; };
    int*   flags = (int*)  alloc(2ull * 2 * SW * 8 * 4);       // [layer][dir][SW][8]
    float* ch_h  = (float*)alloc(4ull * SW * HCD * 4);         // [layer*2+dir][SW][HCD]
    float* ch_c  = (float*)alloc(4ull * SW * HCD * 4);
    const size_t zbytes = (size_t)(p - (char*)d_ws);           // zero: flags + ch_h + ch_c
    float* gates = (float*)alloc(2ull * SW * 512 * 4);         // per-dir char gates / logits tmp
    float* o0s   = (float*)alloc((size_t)SW * 256 * 4);        // layer-0 output, current t only
    float* crepr = (float*)alloc((size_t)SW * 256 * 4);
    float* wG    = (float*)alloc(2ull * SW * 1024 * 4);        // word gate inputs (reused L0->L1)
    float* wo0   = (float*)alloc((size_t)SW * 512 * 4);
    float* wo1   = (float*)alloc((size_t)SW * 512 * 4);
    int*   cidx  = (int*)  alloc((size_t)TC * SW * 4);

    hipMemsetAsync(d_ws, 0, zbytes, stream);
    build_cidx<<<TC * SW / 256, 256, 0, stream>>>(char_ix, cidx);

    // ---- char biLSTM: L0 and L1 interleaved per timestep (o0s is one-step ring) ----
    for (int t = 0; t < TC; ++t) {
        for (int d = 0; d < 2; ++d)
            gemm2<<<dim3(512 / BN, SW / BM), 256, 0, stream>>>(
                char_emb, ECD, cidx + t * SW, cW_ih0 + (size_t)d * 512 * ECD, ECD, ECD,
                ch_h + (size_t)d * SW * HCD, HCD, cW_hh0 + (size_t)d * 512 * HCD, HCD, HCD,
                cb0 + d * 512, gates + (size_t)d * SW * 512, 512, 512);
        for (int d = 0; d < 2; ++d)
            lstm_cell_char<<<SW * HCD / 256, 256, 0, stream>>>(
                gates + (size_t)d * SW * 512, ch_c + (size_t)d * SW * HCD,
                ch_h + (size_t)d * SW * HCD, o0s + d * HCD, nullptr, nullptr, t);
        for (int d = 0; d < 2; ++d)
            gemm2<<<dim3(512 / BN, SW / BM), 256, 0, stream>>>(
                o0s, 256, nullptr, cW_ih1 + (size_t)d * 512 * 256, 256, 256,
                ch_h + (size_t)(2 + d) * SW * HCD, HCD, cW_hh1 + (size_t)d * 512 * HCD, HCD, HCD,
                cb1 + d * 512, gates + (size_t)d * SW * 512, 512, 512);
        for (int d = 0; d < 2; ++d)
            lstm_cell_char<<<SW * HCD / 256, 256, 0, stream>>>(
                gates + (size_t)d * SW * 512, ch_c + (size_t)(2 + d) * SW * HCD,
                ch_h + (size_t)(2 + d) * SW * HCD, nullptr, crepr + d * HCD, char_len, t);
    }

    // ---- word biLSTM layer 0 ----
    for (int d = 0; d < 2; ++d)
        gemm2<<<dim3(1024 / BN, SW / BM), 256, 0, stream>>>(
            word_emb, DWD, word_ix, wW_ih0 + (size_t)d * 1024 * DIND, DIND, DWD,
            crepr, 256, wW_ih0 + (size_t)d * 1024 * DIND + DWD, DIND, 256,
            wb0 + d * 1024, wG + (size_t)d * SW * 1024, 1024, 1024);
    word_scan<<<16, 512, 0, stream>>>(wG, wW_hh0, wo0, flags);

    // ---- word biLSTM layer 1 ----
    for (int d = 0; d < 2; ++d)
        gemm2<<<dim3(1024 / BN, SW / BM), 256, 0, stream>>>(
            wo0, 512, nullptr, wW_ih1 + (size_t)d * 1024 * 512, 512, 512,
            nullptr, 0, nullptr, 0, 0,
            wb1 + d * 1024, wG + (size_t)d * SW * 1024, 1024, 1024);
    word_scan<<<16, 512, 0, stream>>>(wG, wW_hh1, wo1, flags + 2 * SW * 8);

    // ---- logits + log_softmax ----
    gemm2<<<dim3(1, SW / BM), 256, 0, stream>>>(
        wo1, 512, nullptr, out_W, 512, 512,
        nullptr, 0, nullptr, 0, 0,
        out_b, gates, NTAGS, NTAGS);
    logsoftmax50<<<SW * 64 / 256, 256, 0, stream>>>(gates, Y);
}